// Round 5
// baseline (572.610 us; speedup 1.0000x reference)
//
#include <hip/hip_runtime.h>
#include <hip/hip_bf16.h>

typedef float f32x4 __attribute__((ext_vector_type(4)));
typedef __bf16 bf16x8 __attribute__((ext_vector_type(8)));

#define H 1024
#define II 4096
#define NE 16
#define CAP 1024
#define NTOK 2048
#define NSLOT 4096

// ---------------- routing: group top-2, expert top-1, weights ----------------
__global__ __launch_bounds__(256) void k_route(
    const float* __restrict__ x, const float* __restrict__ gw,
    const float* __restrict__ erw, int* __restrict__ eid,
    float* __restrict__ wgt) {
  int t = blockIdx.x * 4 + (threadIdx.x >> 6);
  int lane = threadIdx.x & 63;
  const float* xr = x + (size_t)t * H;
  double acc[20];
#pragma unroll
  for (int j = 0; j < 20; j++) acc[j] = 0.0;
  for (int it = 0; it < 16; ++it) {
    int h = it * 64 + lane;
    float xv = xr[h];
#pragma unroll
    for (int g = 0; g < 4; ++g) acc[g] += (double)xv * (double)gw[g * H + h];
#pragma unroll
    for (int j = 0; j < 16; ++j)
      acc[4 + j] += (double)xv * (double)erw[j * H + h];
  }
#pragma unroll
  for (int j = 0; j < 20; ++j) {
    double v = acc[j];
#pragma unroll
    for (int o = 32; o > 0; o >>= 1) v += __shfl_down(v, o, 64);
    acc[j] = v;
  }
  if (lane == 0) {
    float gl[4];
#pragma unroll
    for (int g = 0; g < 4; g++) gl[g] = (float)acc[g];
    int g1 = 0;
#pragma unroll
    for (int g = 1; g < 4; g++)
      if (gl[g] > gl[g1]) g1 = g;
    int g2 = (g1 == 0) ? 1 : 0;
#pragma unroll
    for (int g = 0; g < 4; g++)
      if (g != g1 && gl[g] > gl[g2]) g2 = g;
    float gm = fmaxf(fmaxf(gl[0], gl[1]), fmaxf(gl[2], gl[3]));
    float s = 0.f;
#pragma unroll
    for (int g = 0; g < 4; g++) s += expf(gl[g] - gm);
    float p[2] = {expf(gl[g1] - gm) / s, expf(gl[g2] - gm) / s};
    int gs[2] = {g1, g2};
#pragma unroll
    for (int k = 0; k < 2; k++) {
      int g = gs[k];
      float el[4];
#pragma unroll
      for (int e2 = 0; e2 < 4; e2++) el[e2] = (float)acc[4 + g * 4 + e2];
      int eb = 0;
#pragma unroll
      for (int e2 = 1; e2 < 4; e2++)
        if (el[e2] > el[eb]) eb = e2;
      float es = 0.f;
#pragma unroll
      for (int e2 = 0; e2 < 4; e2++) es += expf(el[e2] - el[eb]);
      eid[2 * t + k] = g * 4 + eb;
      wgt[2 * t + k] = p[k] * (1.f / es);
    }
  }
}

// ---------------- capacity scan ----------------
__global__ __launch_bounds__(1024) void k_scan(const int* __restrict__ eid,
                                               int* __restrict__ perm,
                                               int* __restrict__ cnt,
                                               int* __restrict__ kept) {
  int wid = threadIdx.x >> 6;
  int lane = threadIdx.x & 63;
  int base = 0;
  for (int it = 0; it < 64; ++it) {
    int slot = it * 64 + lane;
    int e = eid[slot];
    unsigned long long m = __ballot(e == wid);
    if (e == wid) {
      int pos = base + __popcll(m & ((1ull << lane) - 1ull));
      if (pos < CAP) {
        perm[wid * CAP + pos] = slot;
        kept[slot] = 1;
      } else {
        kept[slot] = 0;
      }
    }
    base += __popcll(m);
  }
  if (lane == 0) cnt[wid] = (base < CAP) ? base : CAP;
}

// ---------------- x -> bf16 ----------------
__global__ __launch_bounds__(256) void k_cvtx(const float* __restrict__ x,
                                              __bf16* __restrict__ xb) {
  size_t i = ((size_t)blockIdx.x * 256 + threadIdx.x) * 8;
  f32x4 a = *(const f32x4*)(x + i);
  f32x4 b = *(const f32x4*)(x + i + 4);
  bf16x8 o;
#pragma unroll
  for (int j = 0; j < 4; j++) {
    o[j] = (__bf16)a[j];
    o[j + 4] = (__bf16)b[j];
  }
  *(bf16x8*)(xb + i) = o;
}

#define FENCE_BAR()                                    \
  asm volatile("s_waitcnt lgkmcnt(0)" ::: "memory");   \
  __builtin_amdgcn_sched_barrier(0);                   \
  __builtin_amdgcn_s_barrier();

#define MFMA_BF16(A, B, C) __builtin_amdgcn_mfma_f32_16x16x32_bf16(A, B, C, 0, 0, 0)

// LDS A tile: [2][128 rows][40 elems] bf16 (stride 80B -> 2-way banks, free)
#define ASTRIDE 40

// ---------------- pass 1: act = silu(x@Wg^T) * (x@Wu^T) ----------
// BM=128 slots, per block 128 G-cols + 128 U-cols, BK=32, 256 thr (4 waves).
// Wave owns all 128 M x 32 cols of G and U. Weights: global->reg->cvt (no LDS).
// A: dbuf LDS, one lgkm barrier per step; B prefetch depth 2 (reg ping-pong).
__global__ __launch_bounds__(256, 1) void k_gateup(
    const __bf16* __restrict__ xb, const float* __restrict__ Wg,
    const float* __restrict__ Wu, const int* __restrict__ perm,
    const int* __restrict__ cnt, __bf16* __restrict__ act) {
  __shared__ __bf16 As[2][128 * ASTRIDE];
  __shared__ int slotArr[128];
  const int e = blockIdx.z, nt = blockIdx.x, rt = blockIdx.y;
  const int ce = cnt[e];
  if (ce <= 0 || rt * 128 >= ce) return;
  const int tid = threadIdx.x, lane = tid & 63, w = tid >> 6;
  if (tid < 128) {
    int ridx = rt * 128 + tid;
    slotArr[tid] = perm[e * CAP + (ridx < ce ? ridx : 0)];
  }
  __syncthreads();
  // A staging: thread covers 32B of one row per step
  const int arow = tid >> 1, ahk = tid & 1;
  const __bf16* pA = xb + (size_t)(slotArr[arow] >> 1) * H + ahk * 16;
  const int wAoff = arow * ASTRIDE + ahk * 16;
  // B rows (exclusive per wave)
  const int l15 = lane & 15, lk = lane >> 4;
  const size_t ewg = (size_t)e * II * H;
  const int rb = nt * 128 + w * 32 + l15;
  const float* pG0 = Wg + ewg + (size_t)rb * H + lk * 8;
  const float* pG1 = pG0 + (size_t)16 * H;
  const float* pU0 = Wu + ewg + (size_t)rb * H + lk * 8;
  const float* pU1 = pU0 + (size_t)16 * H;

  f32x4 accG[8][2], accU[8][2];
#pragma unroll
  for (int m = 0; m < 8; m++)
#pragma unroll
    for (int n = 0; n < 2; n++)
#pragma unroll
      for (int i = 0; i < 4; i++) {
        accG[m][n][i] = 0.f;
        accU[m][n][i] = 0.f;
      }

#define DECLB(P) f32x4 P##0l, P##0h, P##1l, P##1h, P##2l, P##2h, P##3l, P##3h
#define LOADB(P, T)                          \
  {                                          \
    const int ko = (T) * 32;                 \
    P##0l = *(const f32x4*)(pG0 + ko);       \
    P##0h = *(const f32x4*)(pG0 + ko + 4);   \
    P##1l = *(const f32x4*)(pG1 + ko);       \
    P##1h = *(const f32x4*)(pG1 + ko + 4);   \
    P##2l = *(const f32x4*)(pU0 + ko);       \
    P##2h = *(const f32x4*)(pU0 + ko + 4);   \
    P##3l = *(const f32x4*)(pU1 + ko);       \
    P##3h = *(const f32x4*)(pU1 + ko + 4);   \
  }
#define CVTB(P, bg0, bg1, bu0, bu1)                  \
  {                                                  \
    _Pragma("unroll") for (int i = 0; i < 4; i++) {  \
      bg0[i] = (__bf16)P##0l[i];                     \
      bg0[i + 4] = (__bf16)P##0h[i];                 \
      bg1[i] = (__bf16)P##1l[i];                     \
      bg1[i + 4] = (__bf16)P##1h[i];                 \
      bu0[i] = (__bf16)P##2l[i];                     \
      bu0[i + 4] = (__bf16)P##2h[i];                 \
      bu1[i] = (__bf16)P##3l[i];                     \
      bu1[i + 4] = (__bf16)P##3h[i];                 \
    }                                                \
  }
#define LOADA(S0, S1, T)                             \
  {                                                  \
    S0 = *(const bf16x8*)(pA + (T) * 32);            \
    S1 = *(const bf16x8*)(pA + (T) * 32 + 8);        \
  }
#define WRITEA(BUF, S0, S1)                          \
  {                                                  \
    *(bf16x8*)&As[BUF][wAoff] = S0;                  \
    *(bf16x8*)&As[BUF][wAoff + 8] = S1;              \
  }
#define GU_MFMA(CB, bg0, bg1, bu0, bu1)                           \
  {                                                               \
    _Pragma("unroll") for (int m = 0; m < 8; m++) {               \
      bf16x8 aF =                                                 \
          *(const bf16x8*)&As[CB][(m * 16 + l15) * ASTRIDE + lk * 8]; \
      accG[m][0] = MFMA_BF16(aF, bg0, accG[m][0]);                \
      accG[m][1] = MFMA_BF16(aF, bg1, accG[m][1]);                \
      accU[m][0] = MFMA_BF16(aF, bu0, accU[m][0]);                \
      accU[m][1] = MFMA_BF16(aF, bu1, accU[m][1]);                \
    }                                                             \
  }

  DECLB(Ba);
  DECLB(Bb);
  bf16x8 aSa0, aSa1, aSb0, aSb1;

  // prologue: A(0),B(0),A(1),B(1); write A(0); reload aSa with A(2)
  LOADA(aSa0, aSa1, 0);
  LOADB(Ba, 0);
  LOADA(aSb0, aSb1, 1);
  LOADB(Bb, 1);
  WRITEA(0, aSa0, aSa1);
  LOADA(aSa0, aSa1, 2);
  FENCE_BAR();

  for (int tt = 0; tt < 16; ++tt) {
    const int t0 = 2 * tt, t1 = t0 + 1;
    // even step: compute buf0 with B(t0)
    {
      if (t0 + 1 < 32) WRITEA(1, aSb0, aSb1);
      if (t0 + 3 < 32) LOADA(aSb0, aSb1, t0 + 3);
      bf16x8 bg0, bg1, bu0, bu1;
      CVTB(Ba, bg0, bg1, bu0, bu1);
      if (t0 + 2 < 32) LOADB(Ba, t0 + 2);
      GU_MFMA(0, bg0, bg1, bu0, bu1);
      FENCE_BAR();
    }
    // odd step: compute buf1 with B(t1)
    {
      if (t1 + 1 < 32) WRITEA(0, aSa0, aSa1);
      if (t1 + 3 < 32) LOADA(aSa0, aSa1, t1 + 3);
      bf16x8 bg0, bg1, bu0, bu1;
      CVTB(Bb, bg0, bg1, bu0, bu1);
      if (t1 + 2 < 32) LOADB(Bb, t1 + 2);
      GU_MFMA(1, bg0, bg1, bu0, bu1);
      if (t1 < 31) FENCE_BAR();
    }
  }
  const int colB = nt * 128 + w * 32;
#pragma unroll
  for (int m = 0; m < 8; m++)
#pragma unroll
    for (int j = 0; j < 2; j++)
#pragma unroll
      for (int i = 0; i < 4; i++) {
        int row = m * 16 + lk * 4 + i;
        if (rt * 128 + row < ce) {
          int slot = slotArr[row];
          float g = accG[m][j][i];
          float u = accU[m][j][i];
          float a = (g / (1.f + __expf(-g))) * u;
          act[(size_t)slot * II + colB + j * 16 + l15] = (__bf16)a;
        }
      }
}

// ---------------- pass 2: y = wgt * (act @ Wd^T) ----------------
// BM=128 slots, BN=128 H-cols, BK=32, 256 thr (4 waves), Wd global->reg.
__global__ __launch_bounds__(256, 2) void k_down(
    const __bf16* __restrict__ act, const float* __restrict__ Wd,
    const int* __restrict__ perm, const int* __restrict__ cnt,
    const float* __restrict__ wgt, float* __restrict__ y) {
  __shared__ __bf16 As[2][128 * ASTRIDE];
  __shared__ int slotArr[128];
  const int e = blockIdx.z, nt = blockIdx.x, rt = blockIdx.y;
  const int ce = cnt[e];
  if (ce <= 0 || rt * 128 >= ce) return;
  const int tid = threadIdx.x, lane = tid & 63, w = tid >> 6;
  if (tid < 128) {
    int ridx = rt * 128 + tid;
    slotArr[tid] = perm[e * CAP + (ridx < ce ? ridx : 0)];
  }
  __syncthreads();
  const int arow = tid >> 1, ahk = tid & 1;
  const __bf16* pA = act + (size_t)slotArr[arow] * II + ahk * 16;
  const int wAoff = arow * ASTRIDE + ahk * 16;
  const int l15 = lane & 15, lk = lane >> 4;
  const int rb = nt * 128 + w * 32 + l15;
  const float* pB0 = Wd + (size_t)e * H * II + (size_t)rb * II + lk * 8;
  const float* pB1 = pB0 + (size_t)16 * II;

  f32x4 acc[8][2];
#pragma unroll
  for (int m = 0; m < 8; m++)
#pragma unroll
    for (int n = 0; n < 2; n++)
#pragma unroll
      for (int i = 0; i < 4; i++) acc[m][n][i] = 0.f;

#define DECLBD(P) f32x4 P##0l, P##0h, P##1l, P##1h
#define LOADBD(P, T)                         \
  {                                          \
    const int ko = (T) * 32;                 \
    P##0l = *(const f32x4*)(pB0 + ko);       \
    P##0h = *(const f32x4*)(pB0 + ko + 4);   \
    P##1l = *(const f32x4*)(pB1 + ko);       \
    P##1h = *(const f32x4*)(pB1 + ko + 4);   \
  }
#define CVTBD(P, b0, b1)                             \
  {                                                  \
    _Pragma("unroll") for (int i = 0; i < 4; i++) {  \
      b0[i] = (__bf16)P##0l[i];                      \
      b0[i + 4] = (__bf16)P##0h[i];                  \
      b1[i] = (__bf16)P##1l[i];                      \
      b1[i + 4] = (__bf16)P##1h[i];                  \
    }                                                \
  }
#define DN_MFMA(CB, b0, b1)                                       \
  {                                                               \
    _Pragma("unroll") for (int m = 0; m < 8; m++) {               \
      bf16x8 aF =                                                 \
          *(const bf16x8*)&As[CB][(m * 16 + l15) * ASTRIDE + lk * 8]; \
      acc[m][0] = MFMA_BF16(aF, b0, acc[m][0]);                   \
      acc[m][1] = MFMA_BF16(aF, b1, acc[m][1]);                   \
    }                                                             \
  }

  DECLBD(Ba);
  DECLBD(Bb);
  bf16x8 aSa0, aSa1, aSb0, aSb1;

  LOADA(aSa0, aSa1, 0);
  LOADBD(Ba, 0);
  LOADA(aSb0, aSb1, 1);
  LOADBD(Bb, 1);
  WRITEA(0, aSa0, aSa1);
  LOADA(aSa0, aSa1, 2);
  FENCE_BAR();

  for (int tt = 0; tt < 64; ++tt) {
    const int t0 = 2 * tt, t1 = t0 + 1;
    {
      if (t0 + 1 < 128) WRITEA(1, aSb0, aSb1);
      if (t0 + 3 < 128) LOADA(aSb0, aSb1, t0 + 3);
      bf16x8 b0, b1;
      CVTBD(Ba, b0, b1);
      if (t0 + 2 < 128) LOADBD(Ba, t0 + 2);
      DN_MFMA(0, b0, b1);
      FENCE_BAR();
    }
    {
      if (t1 + 1 < 128) WRITEA(0, aSa0, aSa1);
      if (t1 + 3 < 128) LOADA(aSa0, aSa1, t1 + 3);
      bf16x8 b0, b1;
      CVTBD(Bb, b0, b1);
      if (t1 + 2 < 128) LOADBD(Bb, t1 + 2);
      DN_MFMA(1, b0, b1);
      if (t1 < 127) FENCE_BAR();
    }
  }
  const int colB = nt * 128 + w * 32;
#pragma unroll
  for (int m = 0; m < 8; m++)
#pragma unroll
    for (int j = 0; j < 2; j++)
#pragma unroll
      for (int i = 0; i < 4; i++) {
        int row = m * 16 + lk * 4 + i;
        if (rt * 128 + row < ce) {
          int slot = slotArr[row];
          y[(size_t)slot * H + colB + j * 16 + l15] =
              wgt[slot] * acc[m][j][i];
        }
      }
}

// ---------------- combine ----------
__global__ __launch_bounds__(256) void k_combine(const float* __restrict__ y,
                                                 const int* __restrict__ kept,
                                                 float* __restrict__ out) {
  int t = blockIdx.x, tid = threadIdx.x;
  const f32x4* y0 = (const f32x4*)(y + (size_t)(2 * t) * H);
  const f32x4* y1 = (const f32x4*)(y + (size_t)(2 * t + 1) * H);
  f32x4 a, b;
#pragma unroll
  for (int i = 0; i < 4; i++) {
    a[i] = 0.f;
    b[i] = 0.f;
  }
  if (kept[2 * t]) a = y0[tid];
  if (kept[2 * t + 1]) b = y1[tid];
  ((f32x4*)out)[(size_t)t * 256 + tid] = a + b;
  if (t == 0 && tid == 0) out[(size_t)NTOK * H] = 0.f;  // aux_loss
}

extern "C" void kernel_launch(void* const* d_in, const int* in_sizes, int n_in,
                              void* d_out, int out_size, void* d_ws,
                              size_t ws_size, hipStream_t stream) {
  const float* x = (const float*)d_in[0];
  const float* gw = (const float*)d_in[1];
  const float* erw = (const float*)d_in[2];
  const float* Wg = (const float*)d_in[3];
  const float* Wu = (const float*)d_in[4];
  const float* Wd = (const float*)d_in[5];
  float* out = (float*)d_out;
  char* ws = (char*)d_ws;
  int* eid = (int*)(ws);
  float* wgt = (float*)(ws + (16 << 10));
  int* kept = (int*)(ws + (32 << 10));
  int* cnt = (int*)(ws + (48 << 10));
  int* perm = (int*)(ws + (64 << 10));
  __bf16* act = (__bf16*)(ws + (128 << 10));                             // 32 MB
  float* yb = (float*)(ws + (128 << 10) + (size_t)NSLOT * II * 2);       // 16 MB
  __bf16* xb = (__bf16*)(ws + (128 << 10) + (size_t)NSLOT * II * 2 +
                         (size_t)NSLOT * H * 4);                         // 4 MB

  k_route<<<NTOK / 4, 256, 0, stream>>>(x, gw, erw, eid, wgt);
  k_scan<<<1, 1024, 0, stream>>>(eid, perm, cnt, kept);
  k_cvtx<<<NTOK * H / 8 / 256, 256, 0, stream>>>(x, xb);
  k_gateup<<<dim3(32, 8, 16), 256, 0, stream>>>(xb, Wg, Wu, perm, cnt, act);
  k_down<<<dim3(8, 8, 16), 256, 0, stream>>>(act, Wd, perm, cnt, wgt, yb);
  k_combine<<<NTOK, 256, 0, stream>>>(yb, kept, out);
}

// Round 6
// 491.489 us; speedup vs baseline: 1.1651x; 1.1651x over previous
//
#include <hip/hip_runtime.h>
#include <hip/hip_bf16.h>

typedef float f32x4 __attribute__((ext_vector_type(4)));
typedef __bf16 bf16x8 __attribute__((ext_vector_type(8)));

#define H 1024
#define II 4096
#define NE 16
#define CAP 1024
#define NTOK 2048
#define NSLOT 4096

// ---------------- routing: group top-2, expert top-1, weights ----------------
__global__ __launch_bounds__(256) void k_route(
    const float* __restrict__ x, const float* __restrict__ gw,
    const float* __restrict__ erw, int* __restrict__ eid,
    float* __restrict__ wgt) {
  int t = blockIdx.x * 4 + (threadIdx.x >> 6);
  int lane = threadIdx.x & 63;
  const float* xr = x + (size_t)t * H;
  double acc[20];
#pragma unroll
  for (int j = 0; j < 20; j++) acc[j] = 0.0;
  for (int it = 0; it < 16; ++it) {
    int h = it * 64 + lane;
    float xv = xr[h];
#pragma unroll
    for (int g = 0; g < 4; ++g) acc[g] += (double)xv * (double)gw[g * H + h];
#pragma unroll
    for (int j = 0; j < 16; ++j)
      acc[4 + j] += (double)xv * (double)erw[j * H + h];
  }
#pragma unroll
  for (int j = 0; j < 20; ++j) {
    double v = acc[j];
#pragma unroll
    for (int o = 32; o > 0; o >>= 1) v += __shfl_down(v, o, 64);
    acc[j] = v;
  }
  if (lane == 0) {
    float gl[4];
#pragma unroll
    for (int g = 0; g < 4; g++) gl[g] = (float)acc[g];
    int g1 = 0;
#pragma unroll
    for (int g = 1; g < 4; g++)
      if (gl[g] > gl[g1]) g1 = g;
    int g2 = (g1 == 0) ? 1 : 0;
#pragma unroll
    for (int g = 0; g < 4; g++)
      if (g != g1 && gl[g] > gl[g2]) g2 = g;
    float gm = fmaxf(fmaxf(gl[0], gl[1]), fmaxf(gl[2], gl[3]));
    float s = 0.f;
#pragma unroll
    for (int g = 0; g < 4; g++) s += expf(gl[g] - gm);
    float p[2] = {expf(gl[g1] - gm) / s, expf(gl[g2] - gm) / s};
    int gs[2] = {g1, g2};
#pragma unroll
    for (int k = 0; k < 2; k++) {
      int g = gs[k];
      float el[4];
#pragma unroll
      for (int e2 = 0; e2 < 4; e2++) el[e2] = (float)acc[4 + g * 4 + e2];
      int eb = 0;
#pragma unroll
      for (int e2 = 1; e2 < 4; e2++)
        if (el[e2] > el[eb]) eb = e2;
      float es = 0.f;
#pragma unroll
      for (int e2 = 0; e2 < 4; e2++) es += expf(el[e2] - el[eb]);
      eid[2 * t + k] = g * 4 + eb;
      wgt[2 * t + k] = p[k] * (1.f / es);
    }
  }
}

// ---------------- capacity scan ----------------
__global__ __launch_bounds__(1024) void k_scan(const int* __restrict__ eid,
                                               int* __restrict__ perm,
                                               int* __restrict__ cnt,
                                               int* __restrict__ kept) {
  int wid = threadIdx.x >> 6;
  int lane = threadIdx.x & 63;
  int base = 0;
  for (int it = 0; it < 64; ++it) {
    int slot = it * 64 + lane;
    int e = eid[slot];
    unsigned long long m = __ballot(e == wid);
    if (e == wid) {
      int pos = base + __popcll(m & ((1ull << lane) - 1ull));
      if (pos < CAP) {
        perm[wid * CAP + pos] = slot;
        kept[slot] = 1;
      } else {
        kept[slot] = 0;
      }
    }
    base += __popcll(m);
  }
  if (lane == 0) cnt[wid] = (base < CAP) ? base : CAP;
}

// ---------------- x -> bf16 ----------------
__global__ __launch_bounds__(256) void k_cvtx(const float* __restrict__ x,
                                              __bf16* __restrict__ xb) {
  size_t i = ((size_t)blockIdx.x * 256 + threadIdx.x) * 8;
  f32x4 a = *(const f32x4*)(x + i);
  f32x4 b = *(const f32x4*)(x + i + 4);
  bf16x8 o;
#pragma unroll
  for (int j = 0; j < 4; j++) {
    o[j] = (__bf16)a[j];
    o[j + 4] = (__bf16)b[j];
  }
  *(bf16x8*)(xb + i) = o;
}

#define FENCE_BAR()                                    \
  asm volatile("s_waitcnt lgkmcnt(0)" ::: "memory");   \
  __builtin_amdgcn_sched_barrier(0);                   \
  __builtin_amdgcn_s_barrier();

#define MFMA_BF16(A, B, C) __builtin_amdgcn_mfma_f32_16x16x32_bf16(A, B, C, 0, 0, 0)

// padded LDS row stride (elems) for BK=32: 18r%32 hits 16 distinct banks
#define ASTR 36

// ---------------- pass 1: act = silu(x@Wg^T) * (x@Wu^T) ----------
// BM=128 slots, BN=64 (G and U), BK=32, 256 thr (2m x 2n waves),
// dbuf LDS (37KB -> 3-4 blocks/CU), 2-deep reg pipeline, lgkm-only barriers.
__global__ __launch_bounds__(256, 3) void k_gateup(
    const __bf16* __restrict__ xb, const float* __restrict__ Wg,
    const float* __restrict__ Wu, const int* __restrict__ perm,
    const int* __restrict__ cnt, __bf16* __restrict__ act) {
  __shared__ __bf16 As[2][128 * ASTR];
  __shared__ __bf16 Gs[2][64 * ASTR];
  __shared__ __bf16 Us[2][64 * ASTR];
  __shared__ int slotArr[128];
  const int e = blockIdx.z, nt = blockIdx.x, rt = blockIdx.y;
  const int ce = cnt[e];
  if (ce <= 0 || rt * 128 >= ce) return;
  const int tid = threadIdx.x, lane = tid & 63, wid = tid >> 6;
  if (tid < 128) {
    int ridx = rt * 128 + tid;
    slotArr[tid] = perm[e * CAP + (ridx < ce ? ridx : 0)];
  }
  __syncthreads();
  // staging roles
  const int arow = tid >> 1, ahalf = tid & 1;                 // A: 32B per thr
  const __bf16* pA = xb + (size_t)(slotArr[arow] >> 1) * H + ahalf * 16;
  const int wA = arow * ASTR + ahalf * 16;
  const int grow = tid >> 2, gq = tid & 3;                    // G/U: 32B per thr
  const size_t ew = (size_t)e * II * H + (size_t)(nt * 64) * H;
  const float* pG = Wg + ew + (size_t)grow * H + gq * 8;
  const float* pU = Wu + ew + (size_t)grow * H + gq * 8;
  const int wG = grow * ASTR + gq * 8;
  const int wm = wid >> 1, wn = wid & 1;
  const int l15 = lane & 15, lk = lane >> 4;

  f32x4 accG[4][2], accU[4][2];
#pragma unroll
  for (int m = 0; m < 4; m++)
#pragma unroll
    for (int n = 0; n < 2; n++)
#pragma unroll
      for (int i = 0; i < 4; i++) {
        accG[m][n][i] = 0.f;
        accU[m][n][i] = 0.f;
      }

  bf16x8 SaA0, SaA1, SbA0, SbA1;
  f32x4 SaG0, SaG1, SaU0, SaU1, SbG0, SbG1, SbU0, SbU1;

#define GU_LOAD(S, T)                          \
  {                                            \
    const int ko = (T) * 32;                   \
    S##A0 = *(const bf16x8*)(pA + ko);         \
    S##A1 = *(const bf16x8*)(pA + ko + 8);     \
    S##G0 = *(const f32x4*)(pG + ko);          \
    S##G1 = *(const f32x4*)(pG + ko + 4);      \
    S##U0 = *(const f32x4*)(pU + ko);          \
    S##U1 = *(const f32x4*)(pU + ko + 4);      \
  }
#define GU_WRITE(B, S)                               \
  {                                                  \
    *(bf16x8*)&As[B][wA] = S##A0;                    \
    *(bf16x8*)&As[B][wA + 8] = S##A1;                \
    bf16x8 fg, fu;                                   \
    _Pragma("unroll") for (int i = 0; i < 4; i++) {  \
      fg[i] = (__bf16)S##G0[i];                      \
      fg[i + 4] = (__bf16)S##G1[i];                  \
      fu[i] = (__bf16)S##U0[i];                      \
      fu[i + 4] = (__bf16)S##U1[i];                  \
    }                                                \
    *(bf16x8*)&Gs[B][wG] = fg;                       \
    *(bf16x8*)&Us[B][wG] = fu;                       \
  }
#define GU_COMPUTE(B)                                                  \
  {                                                                    \
    bf16x8 aF[4], gF[2], uF[2];                                        \
    _Pragma("unroll") for (int m = 0; m < 4; m++)                      \
        aF[m] = *(const bf16x8*)&As[B][(wm * 64 + m * 16 + l15) * ASTR + lk * 8]; \
    _Pragma("unroll") for (int n = 0; n < 2; n++) {                    \
      gF[n] = *(const bf16x8*)&Gs[B][(wn * 32 + n * 16 + l15) * ASTR + lk * 8];   \
      uF[n] = *(const bf16x8*)&Us[B][(wn * 32 + n * 16 + l15) * ASTR + lk * 8];   \
    }                                                                  \
    _Pragma("unroll") for (int m = 0; m < 4; m++)                      \
        _Pragma("unroll") for (int n = 0; n < 2; n++) {                \
      accG[m][n] = MFMA_BF16(aF[m], gF[n], accG[m][n]);                \
      accU[m][n] = MFMA_BF16(aF[m], uF[n], accU[m][n]);                \
    }                                                                  \
  }

  // prologue: Sa<-t0, Sb<-t1, write buf0<-Sa, Sa<-t2
  GU_LOAD(Sa, 0);
  GU_LOAD(Sb, 1);
  GU_WRITE(0, Sa);
  GU_LOAD(Sa, 2);
  FENCE_BAR();
  for (int tt = 0; tt < 16; ++tt) {
    const int t0 = 2 * tt, t1 = t0 + 1;
    // even: buf1 <- Sb(t0+1); Sb <- t0+3; compute buf0 (t0)
    {
      if (t0 + 1 < 32) GU_WRITE(1, Sb);
      if (t0 + 3 < 32) GU_LOAD(Sb, t0 + 3);
      GU_COMPUTE(0);
      FENCE_BAR();
    }
    // odd: buf0 <- Sa(t1+1); Sa <- t1+3; compute buf1 (t1)
    {
      if (t1 + 1 < 32) GU_WRITE(0, Sa);
      if (t1 + 3 < 32) GU_LOAD(Sa, t1 + 3);
      GU_COMPUTE(1);
      if (t1 < 31) FENCE_BAR();
    }
  }
  const int colB = nt * 64 + wn * 32;
#pragma unroll
  for (int m = 0; m < 4; m++)
#pragma unroll
    for (int n = 0; n < 2; n++)
#pragma unroll
      for (int i = 0; i < 4; i++) {
        int row = wm * 64 + m * 16 + lk * 4 + i;
        if (rt * 128 + row < ce) {
          int slot = slotArr[row];
          float g = accG[m][n][i];
          float u = accU[m][n][i];
          float a = (g / (1.f + __expf(-g))) * u;
          act[(size_t)slot * II + colB + n * 16 + l15] = (__bf16)a;
        }
      }
}

// ---------------- pass 2: y = wgt * (act @ Wd^T) ----------------
// BM=128, BN=64, BK=32, 256 thr, dbuf LDS (28KB -> 4-5 blocks/CU).
__global__ __launch_bounds__(256, 4) void k_down(
    const __bf16* __restrict__ act, const float* __restrict__ Wd,
    const int* __restrict__ perm, const int* __restrict__ cnt,
    const float* __restrict__ wgt, float* __restrict__ y) {
  __shared__ __bf16 As[2][128 * ASTR];
  __shared__ __bf16 Ws[2][64 * ASTR];
  __shared__ int slotArr[128];
  const int e = blockIdx.z, nt = blockIdx.x, rt = blockIdx.y;
  const int ce = cnt[e];
  if (ce <= 0 || rt * 128 >= ce) return;
  const int tid = threadIdx.x, lane = tid & 63, wid = tid >> 6;
  if (tid < 128) {
    int ridx = rt * 128 + tid;
    slotArr[tid] = perm[e * CAP + (ridx < ce ? ridx : 0)];
  }
  __syncthreads();
  const int arow = tid >> 1, ahalf = tid & 1;
  const __bf16* pA = act + (size_t)slotArr[arow] * II + ahalf * 16;
  const int wA = arow * ASTR + ahalf * 16;
  const int grow = tid >> 2, gq = tid & 3;
  const float* pW =
      Wd + (size_t)e * H * II + (size_t)(nt * 64 + grow) * II + gq * 8;
  const int wW = grow * ASTR + gq * 8;
  const int wm = wid >> 1, wn = wid & 1;
  const int l15 = lane & 15, lk = lane >> 4;

  f32x4 acc[4][2];
#pragma unroll
  for (int m = 0; m < 4; m++)
#pragma unroll
    for (int n = 0; n < 2; n++)
#pragma unroll
      for (int i = 0; i < 4; i++) acc[m][n][i] = 0.f;

  bf16x8 SaA0, SaA1, SbA0, SbA1;
  f32x4 SaW0, SaW1, SbW0, SbW1;

#define DN_LOAD(S, T)                          \
  {                                            \
    const int ko = (T) * 32;                   \
    S##A0 = *(const bf16x8*)(pA + ko);         \
    S##A1 = *(const bf16x8*)(pA + ko + 8);     \
    S##W0 = *(const f32x4*)(pW + ko);          \
    S##W1 = *(const f32x4*)(pW + ko + 4);      \
  }
#define DN_WRITE(B, S)                               \
  {                                                  \
    *(bf16x8*)&As[B][wA] = S##A0;                    \
    *(bf16x8*)&As[B][wA + 8] = S##A1;                \
    bf16x8 fw;                                       \
    _Pragma("unroll") for (int i = 0; i < 4; i++) {  \
      fw[i] = (__bf16)S##W0[i];                      \
      fw[i + 4] = (__bf16)S##W1[i];                  \
    }                                                \
    *(bf16x8*)&Ws[B][wW] = fw;                       \
  }
#define DN_COMPUTE(B)                                                  \
  {                                                                    \
    bf16x8 aF[4], wF[2];                                               \
    _Pragma("unroll") for (int m = 0; m < 4; m++)                      \
        aF[m] = *(const bf16x8*)&As[B][(wm * 64 + m * 16 + l15) * ASTR + lk * 8]; \
    _Pragma("unroll") for (int n = 0; n < 2; n++)                      \
        wF[n] = *(const bf16x8*)&Ws[B][(wn * 32 + n * 16 + l15) * ASTR + lk * 8]; \
    _Pragma("unroll") for (int m = 0; m < 4; m++)                      \
        _Pragma("unroll") for (int n = 0; n < 2; n++)                  \
            acc[m][n] = MFMA_BF16(aF[m], wF[n], acc[m][n]);            \
  }

  DN_LOAD(Sa, 0);
  DN_LOAD(Sb, 1);
  DN_WRITE(0, Sa);
  DN_LOAD(Sa, 2);
  FENCE_BAR();
  for (int tt = 0; tt < 64; ++tt) {
    const int t0 = 2 * tt, t1 = t0 + 1;
    {
      if (t0 + 1 < 128) DN_WRITE(1, Sb);
      if (t0 + 3 < 128) DN_LOAD(Sb, t0 + 3);
      DN_COMPUTE(0);
      FENCE_BAR();
    }
    {
      if (t1 + 1 < 128) DN_WRITE(0, Sa);
      if (t1 + 3 < 128) DN_LOAD(Sa, t1 + 3);
      DN_COMPUTE(1);
      if (t1 < 127) FENCE_BAR();
    }
  }
  const int colB = nt * 64 + wn * 32;
#pragma unroll
  for (int m = 0; m < 4; m++)
#pragma unroll
    for (int n = 0; n < 2; n++)
#pragma unroll
      for (int i = 0; i < 4; i++) {
        int row = wm * 64 + m * 16 + lk * 4 + i;
        if (rt * 128 + row < ce) {
          int slot = slotArr[row];
          y[(size_t)slot * H + colB + n * 16 + l15] =
              wgt[slot] * acc[m][n][i];
        }
      }
}

// ---------------- combine ----------
__global__ __launch_bounds__(256) void k_combine(const float* __restrict__ y,
                                                 const int* __restrict__ kept,
                                                 float* __restrict__ out) {
  int t = blockIdx.x, tid = threadIdx.x;
  const f32x4* y0 = (const f32x4*)(y + (size_t)(2 * t) * H);
  const f32x4* y1 = (const f32x4*)(y + (size_t)(2 * t + 1) * H);
  f32x4 a, b;
#pragma unroll
  for (int i = 0; i < 4; i++) {
    a[i] = 0.f;
    b[i] = 0.f;
  }
  if (kept[2 * t]) a = y0[tid];
  if (kept[2 * t + 1]) b = y1[tid];
  ((f32x4*)out)[(size_t)t * 256 + tid] = a + b;
  if (t == 0 && tid == 0) out[(size_t)NTOK * H] = 0.f;  // aux_loss
}

extern "C" void kernel_launch(void* const* d_in, const int* in_sizes, int n_in,
                              void* d_out, int out_size, void* d_ws,
                              size_t ws_size, hipStream_t stream) {
  const float* x = (const float*)d_in[0];
  const float* gw = (const float*)d_in[1];
  const float* erw = (const float*)d_in[2];
  const float* Wg = (const float*)d_in[3];
  const float* Wu = (const float*)d_in[4];
  const float* Wd = (const float*)d_in[5];
  float* out = (float*)d_out;
  char* ws = (char*)d_ws;
  int* eid = (int*)(ws);
  float* wgt = (float*)(ws + (16 << 10));
  int* kept = (int*)(ws + (32 << 10));
  int* cnt = (int*)(ws + (48 << 10));
  int* perm = (int*)(ws + (64 << 10));
  __bf16* act = (__bf16*)(ws + (128 << 10));                             // 32 MB
  float* yb = (float*)(ws + (128 << 10) + (size_t)NSLOT * II * 2);       // 16 MB
  __bf16* xb = (__bf16*)(ws + (128 << 10) + (size_t)NSLOT * II * 2 +
                         (size_t)NSLOT * H * 4);                         // 4 MB

  k_route<<<NTOK / 4, 256, 0, stream>>>(x, gw, erw, eid, wgt);
  k_scan<<<1, 1024, 0, stream>>>(eid, perm, cnt, kept);
  k_cvtx<<<NTOK * H / 8 / 256, 256, 0, stream>>>(x, xb);
  k_gateup<<<dim3(64, 8, 16), 256, 0, stream>>>(xb, Wg, Wu, perm, cnt, act);
  k_down<<<dim3(16, 8, 16), 256, 0, stream>>>(act, Wd, perm, cnt, wgt, yb);
  k_combine<<<NTOK, 256, 0, stream>>>(yb, kept, out);
}

// Round 7
// 402.829 us; speedup vs baseline: 1.4215x; 1.2201x over previous
//
#include <hip/hip_runtime.h>
#include <hip/hip_bf16.h>

typedef float f32x4 __attribute__((ext_vector_type(4)));
typedef __bf16 bf16x8 __attribute__((ext_vector_type(8)));

#define H 1024
#define II 4096
#define NE 16
#define CAP 1024
#define NTOK 2048
#define NSLOT 4096

// ---------------- routing: group top-2, expert top-1, weights ----------------
__global__ __launch_bounds__(256) void k_route(
    const float* __restrict__ x, const float* __restrict__ gw,
    const float* __restrict__ erw, int* __restrict__ eid,
    float* __restrict__ wgt) {
  int t = blockIdx.x * 4 + (threadIdx.x >> 6);
  int lane = threadIdx.x & 63;
  const float* xr = x + (size_t)t * H;
  double acc[20];
#pragma unroll
  for (int j = 0; j < 20; j++) acc[j] = 0.0;
  for (int it = 0; it < 16; ++it) {
    int h = it * 64 + lane;
    float xv = xr[h];
#pragma unroll
    for (int g = 0; g < 4; ++g) acc[g] += (double)xv * (double)gw[g * H + h];
#pragma unroll
    for (int j = 0; j < 16; ++j)
      acc[4 + j] += (double)xv * (double)erw[j * H + h];
  }
#pragma unroll
  for (int j = 0; j < 20; ++j) {
    double v = acc[j];
#pragma unroll
    for (int o = 32; o > 0; o >>= 1) v += __shfl_down(v, o, 64);
    acc[j] = v;
  }
  if (lane == 0) {
    float gl[4];
#pragma unroll
    for (int g = 0; g < 4; g++) gl[g] = (float)acc[g];
    int g1 = 0;
#pragma unroll
    for (int g = 1; g < 4; g++)
      if (gl[g] > gl[g1]) g1 = g;
    int g2 = (g1 == 0) ? 1 : 0;
#pragma unroll
    for (int g = 0; g < 4; g++)
      if (g != g1 && gl[g] > gl[g2]) g2 = g;
    float gm = fmaxf(fmaxf(gl[0], gl[1]), fmaxf(gl[2], gl[3]));
    float s = 0.f;
#pragma unroll
    for (int g = 0; g < 4; g++) s += expf(gl[g] - gm);
    float p[2] = {expf(gl[g1] - gm) / s, expf(gl[g2] - gm) / s};
    int gs[2] = {g1, g2};
#pragma unroll
    for (int k = 0; k < 2; k++) {
      int g = gs[k];
      float el[4];
#pragma unroll
      for (int e2 = 0; e2 < 4; e2++) el[e2] = (float)acc[4 + g * 4 + e2];
      int eb = 0;
#pragma unroll
      for (int e2 = 1; e2 < 4; e2++)
        if (el[e2] > el[eb]) eb = e2;
      float es = 0.f;
#pragma unroll
      for (int e2 = 0; e2 < 4; e2++) es += expf(el[e2] - el[eb]);
      eid[2 * t + k] = g * 4 + eb;
      wgt[2 * t + k] = p[k] * (1.f / es);
    }
  }
}

// ---------------- capacity scan (eid prefetched to regs) ----------------
__global__ __launch_bounds__(1024) void k_scan(const int* __restrict__ eid,
                                               int* __restrict__ perm,
                                               int* __restrict__ cnt,
                                               int* __restrict__ kept) {
  int wid = threadIdx.x >> 6;
  int lane = threadIdx.x & 63;
  int ne[64];
#pragma unroll
  for (int it = 0; it < 64; ++it) ne[it] = eid[it * 64 + lane];
  int base = 0;
#pragma unroll
  for (int it = 0; it < 64; ++it) {
    int slot = it * 64 + lane;
    int e = ne[it];
    unsigned long long m = __ballot(e == wid);
    if (e == wid) {
      int pos = base + __popcll(m & ((1ull << lane) - 1ull));
      if (pos < CAP) {
        perm[wid * CAP + pos] = slot;
        kept[slot] = 1;
      } else {
        kept[slot] = 0;
      }
    }
    base += __popcll(m);
  }
  if (lane == 0) cnt[wid] = (base < CAP) ? base : CAP;
}

// ---------------- x -> bf16 ----------------
__global__ __launch_bounds__(256) void k_cvtx(const float* __restrict__ x,
                                              __bf16* __restrict__ xb) {
  size_t i = ((size_t)blockIdx.x * 256 + threadIdx.x) * 8;
  f32x4 a = *(const f32x4*)(x + i);
  f32x4 b = *(const f32x4*)(x + i + 4);
  bf16x8 o;
#pragma unroll
  for (int j = 0; j < 4; j++) {
    o[j] = (__bf16)a[j];
    o[j + 4] = (__bf16)b[j];
  }
  *(bf16x8*)(xb + i) = o;
}

#define FENCE_BAR()                                    \
  asm volatile("s_waitcnt lgkmcnt(0)" ::: "memory");   \
  __builtin_amdgcn_sched_barrier(0);                   \
  __builtin_amdgcn_s_barrier();

#define MFMA_BF16(A, B, C) __builtin_amdgcn_mfma_f32_16x16x32_bf16(A, B, C, 0, 0, 0)

#define ASTR 36  // padded LDS row stride (elems), BK=32

// ---------------- pass 1: act = silu(x@Wg^T) * (x@Wu^T) ----------
// BM=128, BN=64(G)+64(U), BK=32, 256 thr (2m x 2n waves),
// depth-4 register pipeline over dbuf LDS, lgkm-only barriers.
__global__ __launch_bounds__(256, 2) void k_gateup(
    const __bf16* __restrict__ xb, const float* __restrict__ Wg,
    const float* __restrict__ Wu, const int* __restrict__ perm,
    const int* __restrict__ cnt, __bf16* __restrict__ act) {
  __shared__ __bf16 As[2][128 * ASTR];
  __shared__ __bf16 Gs[2][64 * ASTR];
  __shared__ __bf16 Us[2][64 * ASTR];
  __shared__ int slotArr[128];
  const int e = blockIdx.z, nt = blockIdx.x, rt = blockIdx.y;
  const int ce = cnt[e];
  if (ce <= 0 || rt * 128 >= ce) return;
  const int tid = threadIdx.x, lane = tid & 63, wid = tid >> 6;
  if (tid < 128) {
    int ridx = rt * 128 + tid;
    slotArr[tid] = perm[e * CAP + (ridx < ce ? ridx : 0)];
  }
  __syncthreads();
  const int arow = tid >> 1, ahalf = tid & 1;  // A: 32B per thr
  const __bf16* pA = xb + (size_t)(slotArr[arow] >> 1) * H + ahalf * 16;
  const int wA = arow * ASTR + ahalf * 16;
  const int grow = tid >> 2, gq = tid & 3;  // G/U: 32B per thr
  const size_t ew = (size_t)e * II * H + (size_t)(nt * 64) * H;
  const float* pG = Wg + ew + (size_t)grow * H + gq * 8;
  const float* pU = Wu + ew + (size_t)grow * H + gq * 8;
  const int wG = grow * ASTR + gq * 8;
  const int wm = wid >> 1, wn = wid & 1;
  const int l15 = lane & 15, lk = lane >> 4;

  f32x4 accG[4][2], accU[4][2];
#pragma unroll
  for (int m = 0; m < 4; m++)
#pragma unroll
    for (int n = 0; n < 2; n++)
#pragma unroll
      for (int i = 0; i < 4; i++) {
        accG[m][n][i] = 0.f;
        accU[m][n][i] = 0.f;
      }

  bf16x8 SA[4][2];
  f32x4 SG[4][2], SU[4][2];

#define GU_LOAD(s, T)                           \
  {                                             \
    const int ko = (T) * 32;                    \
    SA[s][0] = *(const bf16x8*)(pA + ko);       \
    SA[s][1] = *(const bf16x8*)(pA + ko + 8);   \
    SG[s][0] = *(const f32x4*)(pG + ko);        \
    SG[s][1] = *(const f32x4*)(pG + ko + 4);    \
    SU[s][0] = *(const f32x4*)(pU + ko);        \
    SU[s][1] = *(const f32x4*)(pU + ko + 4);    \
  }
#define GU_WRITE(B, s)                               \
  {                                                  \
    *(bf16x8*)&As[B][wA] = SA[s][0];                 \
    *(bf16x8*)&As[B][wA + 8] = SA[s][1];             \
    bf16x8 fg, fu;                                   \
    _Pragma("unroll") for (int i = 0; i < 4; i++) {  \
      fg[i] = (__bf16)SG[s][0][i];                   \
      fg[i + 4] = (__bf16)SG[s][1][i];               \
      fu[i] = (__bf16)SU[s][0][i];                   \
      fu[i + 4] = (__bf16)SU[s][1][i];               \
    }                                                \
    *(bf16x8*)&Gs[B][wG] = fg;                       \
    *(bf16x8*)&Us[B][wG] = fu;                       \
  }
#define GU_COMPUTE(B)                                                  \
  {                                                                    \
    bf16x8 aF[4], gF[2], uF[2];                                        \
    _Pragma("unroll") for (int m = 0; m < 4; m++)                      \
        aF[m] = *(const bf16x8*)&As[B][(wm * 64 + m * 16 + l15) * ASTR + lk * 8]; \
    _Pragma("unroll") for (int n = 0; n < 2; n++) {                    \
      gF[n] = *(const bf16x8*)&Gs[B][(wn * 32 + n * 16 + l15) * ASTR + lk * 8];   \
      uF[n] = *(const bf16x8*)&Us[B][(wn * 32 + n * 16 + l15) * ASTR + lk * 8];   \
    }                                                                  \
    _Pragma("unroll") for (int m = 0; m < 4; m++)                      \
        _Pragma("unroll") for (int n = 0; n < 2; n++) {                \
      accG[m][n] = MFMA_BF16(aF[m], gF[n], accG[m][n]);                \
      accU[m][n] = MFMA_BF16(aF[m], uF[n], accU[m][n]);                \
    }                                                                  \
  }

  // prologue: 4 stages in flight, buf0 <- tile0, S0 reloads tile4
  GU_LOAD(0, 0);
  GU_LOAD(1, 1);
  GU_LOAD(2, 2);
  GU_LOAD(3, 3);
  GU_WRITE(0, 0);
  GU_LOAD(0, 4);
  FENCE_BAR();
  for (int tb = 0; tb < 4; ++tb) {
#pragma unroll
    for (int j = 0; j < 8; ++j) {
      const int t = tb * 8 + j;
      const int s = (j + 1) & 3;  // == (t+1)&3
      const int buf = j & 1;      // == t&1
      if (t + 1 < 32) GU_WRITE(buf ^ 1, s);
      if (t + 5 < 32) GU_LOAD(s, t + 5);
      GU_COMPUTE(buf);
      if (t + 1 < 32) FENCE_BAR();
    }
  }
  const int colB = nt * 64 + wn * 32;
#pragma unroll
  for (int m = 0; m < 4; m++)
#pragma unroll
    for (int n = 0; n < 2; n++)
#pragma unroll
      for (int i = 0; i < 4; i++) {
        int row = wm * 64 + m * 16 + lk * 4 + i;
        if (rt * 128 + row < ce) {
          int slot = slotArr[row];
          float g = accG[m][n][i];
          float u = accU[m][n][i];
          float a = (g / (1.f + __expf(-g))) * u;
          act[(size_t)slot * II + colB + n * 16 + l15] = (__bf16)a;
        }
      }
}

// ---------------- pass 2: y = wgt * (act @ Wd^T), split-K x2 ----------------
// BM=128, BN=64, BK=32, 256 thr, depth-4 pipeline, K-half per block.
__global__ __launch_bounds__(256, 3) void k_down(
    const __bf16* __restrict__ act, const float* __restrict__ Wd,
    const int* __restrict__ perm, const int* __restrict__ cnt,
    const float* __restrict__ wgt, float* __restrict__ yb0,
    float* __restrict__ yb1) {
  __shared__ __bf16 As[2][128 * ASTR];
  __shared__ __bf16 Ws[2][64 * ASTR];
  __shared__ int slotArr[128];
  const int e = blockIdx.z, nt = blockIdx.x;
  const int rt = blockIdx.y & 7, sk = blockIdx.y >> 3;
  const int ce = cnt[e];
  if (ce <= 0 || rt * 128 >= ce) return;
  const int tid = threadIdx.x, lane = tid & 63, wid = tid >> 6;
  if (tid < 128) {
    int ridx = rt * 128 + tid;
    slotArr[tid] = perm[e * CAP + (ridx < ce ? ridx : 0)];
  }
  __syncthreads();
  const int KB = sk * 2048;
  const int arow = tid >> 1, ahalf = tid & 1;
  const __bf16* pA = act + (size_t)slotArr[arow] * II + KB + ahalf * 16;
  const int wA = arow * ASTR + ahalf * 16;
  const int grow = tid >> 2, gq = tid & 3;
  const float* pW =
      Wd + (size_t)e * H * II + (size_t)(nt * 64 + grow) * II + KB + gq * 8;
  const int wW = grow * ASTR + gq * 8;
  const int wm = wid >> 1, wn = wid & 1;
  const int l15 = lane & 15, lk = lane >> 4;

  f32x4 acc[4][2];
#pragma unroll
  for (int m = 0; m < 4; m++)
#pragma unroll
    for (int n = 0; n < 2; n++)
#pragma unroll
      for (int i = 0; i < 4; i++) acc[m][n][i] = 0.f;

  bf16x8 SA[4][2];
  f32x4 SW[4][2];

#define DN_LOAD(s, T)                           \
  {                                             \
    const int ko = (T) * 32;                    \
    SA[s][0] = *(const bf16x8*)(pA + ko);       \
    SA[s][1] = *(const bf16x8*)(pA + ko + 8);   \
    SW[s][0] = *(const f32x4*)(pW + ko);        \
    SW[s][1] = *(const f32x4*)(pW + ko + 4);    \
  }
#define DN_WRITE(B, s)                               \
  {                                                  \
    *(bf16x8*)&As[B][wA] = SA[s][0];                 \
    *(bf16x8*)&As[B][wA + 8] = SA[s][1];             \
    bf16x8 fw;                                       \
    _Pragma("unroll") for (int i = 0; i < 4; i++) {  \
      fw[i] = (__bf16)SW[s][0][i];                   \
      fw[i + 4] = (__bf16)SW[s][1][i];               \
    }                                                \
    *(bf16x8*)&Ws[B][wW] = fw;                       \
  }
#define DN_COMPUTE(B)                                                  \
  {                                                                    \
    bf16x8 aF[4], wF[2];                                               \
    _Pragma("unroll") for (int m = 0; m < 4; m++)                      \
        aF[m] = *(const bf16x8*)&As[B][(wm * 64 + m * 16 + l15) * ASTR + lk * 8]; \
    _Pragma("unroll") for (int n = 0; n < 2; n++)                      \
        wF[n] = *(const bf16x8*)&Ws[B][(wn * 32 + n * 16 + l15) * ASTR + lk * 8]; \
    _Pragma("unroll") for (int m = 0; m < 4; m++)                      \
        _Pragma("unroll") for (int n = 0; n < 2; n++)                  \
            acc[m][n] = MFMA_BF16(aF[m], wF[n], acc[m][n]);            \
  }

  DN_LOAD(0, 0);
  DN_LOAD(1, 1);
  DN_LOAD(2, 2);
  DN_LOAD(3, 3);
  DN_WRITE(0, 0);
  DN_LOAD(0, 4);
  FENCE_BAR();
  for (int tb = 0; tb < 8; ++tb) {
#pragma unroll
    for (int j = 0; j < 8; ++j) {
      const int t = tb * 8 + j;
      const int s = (j + 1) & 3;
      const int buf = j & 1;
      if (t + 1 < 64) DN_WRITE(buf ^ 1, s);
      if (t + 5 < 64) DN_LOAD(s, t + 5);
      DN_COMPUTE(buf);
      if (t + 1 < 64) FENCE_BAR();
    }
  }
  float* yp = sk ? yb1 : yb0;
  const int colB = nt * 64 + wn * 32;
#pragma unroll
  for (int m = 0; m < 4; m++)
#pragma unroll
    for (int n = 0; n < 2; n++)
#pragma unroll
      for (int i = 0; i < 4; i++) {
        int row = wm * 64 + m * 16 + lk * 4 + i;
        if (rt * 128 + row < ce) {
          int slot = slotArr[row];
          yp[(size_t)slot * H + colB + n * 16 + l15] =
              wgt[slot] * acc[m][n][i];
        }
      }
}

// ---------------- combine: out[t] = sum over slot pair + K-splits ----------
__global__ __launch_bounds__(256) void k_combine(const float* __restrict__ y0p,
                                                 const float* __restrict__ y1p,
                                                 const int* __restrict__ kept,
                                                 float* __restrict__ out) {
  int t = blockIdx.x, tid = threadIdx.x;
  size_t o0 = (size_t)(2 * t) * H, o1 = (size_t)(2 * t + 1) * H;
  f32x4 a, b;
#pragma unroll
  for (int i = 0; i < 4; i++) {
    a[i] = 0.f;
    b[i] = 0.f;
  }
  if (kept[2 * t])
    a = ((const f32x4*)(y0p + o0))[tid] + ((const f32x4*)(y1p + o0))[tid];
  if (kept[2 * t + 1])
    b = ((const f32x4*)(y0p + o1))[tid] + ((const f32x4*)(y1p + o1))[tid];
  ((f32x4*)out)[(size_t)t * 256 + tid] = a + b;
  if (t == 0 && tid == 0) out[(size_t)NTOK * H] = 0.f;  // aux_loss
}

extern "C" void kernel_launch(void* const* d_in, const int* in_sizes, int n_in,
                              void* d_out, int out_size, void* d_ws,
                              size_t ws_size, hipStream_t stream) {
  const float* x = (const float*)d_in[0];
  const float* gw = (const float*)d_in[1];
  const float* erw = (const float*)d_in[2];
  const float* Wg = (const float*)d_in[3];
  const float* Wu = (const float*)d_in[4];
  const float* Wd = (const float*)d_in[5];
  float* out = (float*)d_out;
  char* ws = (char*)d_ws;
  int* eid = (int*)(ws);
  float* wgt = (float*)(ws + (16 << 10));
  int* kept = (int*)(ws + (32 << 10));
  int* cnt = (int*)(ws + (48 << 10));
  int* perm = (int*)(ws + (64 << 10));
  size_t off = 128 << 10;
  __bf16* act = (__bf16*)(ws + off);           // 32 MB
  off += (size_t)NSLOT * II * 2;
  float* yb0 = (float*)(ws + off);             // 16 MB
  off += (size_t)NSLOT * H * 4;
  float* yb1 = (float*)(ws + off);             // 16 MB
  off += (size_t)NSLOT * H * 4;
  __bf16* xb = (__bf16*)(ws + off);            // 4 MB

  k_route<<<NTOK / 4, 256, 0, stream>>>(x, gw, erw, eid, wgt);
  k_scan<<<1, 1024, 0, stream>>>(eid, perm, cnt, kept);
  k_cvtx<<<NTOK * H / 8 / 256, 256, 0, stream>>>(x, xb);
  k_gateup<<<dim3(64, 8, 16), 256, 0, stream>>>(xb, Wg, Wu, perm, cnt, act);
  k_down<<<dim3(16, 16, 16), 256, 0, stream>>>(act, Wd, perm, cnt, wgt, yb0, yb1);
  k_combine<<<NTOK, 256, 0, stream>>>(yb0, yb1, kept, out);
}